// Round 3
// baseline (77.611 us; speedup 1.0000x reference)
//
#include <hip/hip_runtime.h>

#define BATCH 16
#define PDEG  3          // P == Q == 3
#define MAXSPAN 127      // M == N == 127
#define KLEN  132        // knots per batch: M + P + 2
#define NSAMP 256        // SU == SV
#define NSPANS 126       // KLEN - 2*PDEG
#define GRID_PTS 128     // M+1 == N+1
#define ROWF (GRID_PTS * 3)   // floats per control row = 384
#define SU_PER_BLK 16    // su rows per block

// Span search + Cox-de Boor (degree 3), f64, faithful to reference:
// masked first-argmin tie semantics + where() fallbacks. kn = normalized
// knot vector in LDS (f64).
__device__ __forceinline__ int basis1(const double* __restrict__ kn,
                                      double t, double Ni[PDEG + 1])
{
    // span: first-argmin over masked = (d > EPS ? d : 1.0), d = t - K[j+deg]
    double best = 1.0e300;
    int jmin = 0;
    for (int j = 0; j < NSPANS; ++j) {
        double d = t - kn[j + PDEG];
        double m = (d > 1.0e-8) ? d : 1.0;
        if (m < best) { best = m; jmin = j; }   // strict <: keeps first min
    }
    int span = jmin + PDEG;
    if (span > MAXSPAN) span = MAXSPAN;

    Ni[0] = 1.0;
    for (int k = 1; k <= PDEG; ++k) {
        double saved = 0.0;
        for (int r = 0; r < k; ++r) {
            double K1 = kn[span + r + 1];
            double K2 = kn[span + 1 - k + r];
            double denom = (K1 - t) + (t - K2);
            double temp = (denom == 0.0) ? 1.0e-4 : (Ni[r] / denom);
            Ni[r] = saved + (K1 - t) * temp;
            saved = (t - K2) * temp;
        }
        Ni[k] = saved;
    }
    return span;
}

// ONE fused kernel. grid = (16 su-groups, 16 batches), 512 threads.
// Phase A: both knot scans concurrently (threads 0..131 -> U, 256..387 -> V),
//          double-buffered Hillis-Steele, 1 barrier/step.
// Phase B: v-basis for all 256 sv (threads 0..255) in parallel with u-basis
//          for this block's 16 su (threads 256..271). Results in LDS.
// Phase C: 8 eval iterations x 2 su-rows, double-buffered s_tmp, 1 barrier
//          per iteration.
__global__ void __launch_bounds__(512)
surf_kernel(const float* __restrict__ ctrl,
            const float* __restrict__ knot_u,
            const float* __restrict__ knot_v,
            const float* __restrict__ u_arr,
            const float* __restrict__ v_arr,
            float* __restrict__ out)
{
    __shared__ double sU[2][KLEN];
    __shared__ double sV[2][KLEN];
    __shared__ __align__(16) float sNv[NSAMP][4];
    __shared__ int   sSv[NSAMP];
    __shared__ __align__(16) float sNu[SU_PER_BLK][4];
    __shared__ int   sSu[SU_PER_BLK];
    __shared__ float s_tmp[2][2][ROWF];         // [dbuf][su-row][col]

    const int t   = threadIdx.x;
    const int su0 = blockIdx.x * SU_PER_BLK;
    const int b   = blockIdx.y;

    // ---- Phase A: load + clamp knots (both axes), then scan concurrently
    if (t < KLEN) {
        float w = knot_u[b * KLEN + t];
        sU[0][t] = (w < 0.0f) ? 1.0e-4 : (double)w;
    } else if (t >= 256 && t < 256 + KLEN) {
        const int i = t - 256;
        float w = knot_v[b * KLEN + i];
        sV[0][i] = (w < 0.0f) ? 1.0e-4 : (double)w;
    }
    __syncthreads();

    int sb = 0;
    for (int off = 1; off < KLEN; off <<= 1) {
        if (t < KLEN) {
            double v = sU[sb][t];
            if (t >= off) v += sU[sb][t - off];
            sU[sb ^ 1][t] = v;
        } else if (t >= 256 && t < 256 + KLEN) {
            const int i = t - 256;
            double v = sV[sb][i];
            if (i >= off) v += sV[sb][i - off];
            sV[sb ^ 1][i] = v;
        }
        __syncthreads();
        sb ^= 1;
    }
    // normalize scan result (in buffer sb) into buffer sb^1
    if (t < KLEN) {
        const double k0  = sU[sb][0];
        const double inv = 1.0 / (sU[sb][KLEN - 1] - k0);
        sU[sb ^ 1][t] = (sU[sb][t] - k0) * inv;
    } else if (t >= 256 && t < 256 + KLEN) {
        const int i = t - 256;
        const double k0  = sV[sb][0];
        const double inv = 1.0 / (sV[sb][KLEN - 1] - k0);
        sV[sb ^ 1][i] = (sV[sb][i] - k0) * inv;
    }
    __syncthreads();
    const double* __restrict__ knU = sU[sb ^ 1];
    const double* __restrict__ knV = sV[sb ^ 1];

    // ---- Phase B: basis. v for all 256 samples; u for this block's 16 rows.
    if (t < NSAMP) {
        double Ni[PDEG + 1];
        const int span = basis1(knV, (double)v_arr[t], Ni);
        float4 o4;
        o4.x = (float)Ni[0]; o4.y = (float)Ni[1];
        o4.z = (float)Ni[2]; o4.w = (float)Ni[3];
        *(float4*)&sNv[t][0] = o4;
        sSv[t] = span;
    } else if (t < NSAMP + SU_PER_BLK) {
        const int j = t - NSAMP;
        double Ni[PDEG + 1];
        const int span = basis1(knU, (double)u_arr[su0 + j], Ni);
        float4 o4;
        o4.x = (float)Ni[0]; o4.y = (float)Ni[1];
        o4.z = (float)Ni[2]; o4.w = (float)Ni[3];
        *(float4*)&sNu[j][0] = o4;
        sSu[j] = span;
    }
    __syncthreads();

    // ---- Phase C: eval. 8 iterations, 2 su-rows per iteration.
    const int r  = t >> 8;          // output row within pair (0/1)
    const int sv = t & 255;
    for (int i = 0; i < SU_PER_BLK / 2; ++i) {
        const int buf = i & 1;
        // phase 1: threads 0..191 compute tmp[pr][c] = sum_p nu[p]*row_p[c]
        if (t < 192) {
            const int pr = (t >= 96) ? 1 : 0;
            const int c  = t - pr * 96;
            const int sl = 2 * i + pr;
            const int us = sSu[sl];
            const float4 nu4 = *(const float4*)&sNu[sl][0];
            const float4* __restrict__ r0 = (const float4*)
                (ctrl + ((size_t)b * GRID_PTS + (size_t)(us - PDEG)) * ROWF);
            float4 a0 = r0[0 * 96 + c];
            float4 a1 = r0[1 * 96 + c];
            float4 a2 = r0[2 * 96 + c];
            float4 a3 = r0[3 * 96 + c];
            float4 t4;
            t4.x = nu4.x * a0.x + nu4.y * a1.x + nu4.z * a2.x + nu4.w * a3.x;
            t4.y = nu4.x * a0.y + nu4.y * a1.y + nu4.z * a2.y + nu4.w * a3.y;
            t4.z = nu4.x * a0.z + nu4.y * a1.z + nu4.z * a2.z + nu4.w * a3.z;
            t4.w = nu4.x * a0.w + nu4.y * a1.w + nu4.z * a2.w + nu4.w * a3.w;
            ((float4*)s_tmp[buf][pr])[c] = t4;
        }
        __syncthreads();
        // phase 2: all 512 threads contract over q and store.
        // Safe with ONE barrier/iter: iteration i+2 re-writes s_tmp[buf] only
        // after barrier@i+1, which every thread reaches only after finishing
        // this read.
        {
            const int sl = 2 * i + r;
            const int vs = sSv[sv];
            const float4 nv4 = *(const float4*)&sNv[sv][0];
            const float* tp = s_tmp[buf][r] + (vs - PDEG) * 3;
            float acc0 = 0.f, acc1 = 0.f, acc2 = 0.f;
#pragma unroll
            for (int q = 0; q < 4; ++q) {
                const float w = (q == 0) ? nv4.x : (q == 1) ? nv4.y
                              : (q == 2) ? nv4.z : nv4.w;
                acc0 += w * tp[q * 3 + 0];
                acc1 += w * tp[q * 3 + 1];
                acc2 += w * tp[q * 3 + 2];
            }
            const size_t o = (((size_t)b * NSAMP + (size_t)(su0 + sl)) * NSAMP
                              + (size_t)sv) * 3;
            out[o + 0] = acc0;
            out[o + 1] = acc1;
            out[o + 2] = acc2;
        }
    }
}

extern "C" void kernel_launch(void* const* d_in, const int* in_sizes, int n_in,
                              void* d_out, int out_size, void* d_ws, size_t ws_size,
                              hipStream_t stream) {
    const float* ctrl   = (const float*)d_in[0];  // (16,128,128,3)
    const float* knot_u = (const float*)d_in[1];  // (16,132)
    const float* knot_v = (const float*)d_in[2];  // (16,132)
    const float* u      = (const float*)d_in[3];  // (256,)
    const float* v      = (const float*)d_in[4];  // (256,)
    float* out = (float*)d_out;                   // (16,256,256,3)

    dim3 grid(NSAMP / SU_PER_BLK, BATCH);         // (16, 16) = 256 blocks
    surf_kernel<<<grid, 512, 0, stream>>>(ctrl, knot_u, knot_v, u, v, out);
}

// Round 4
// 74.678 us; speedup vs baseline: 1.0393x; 1.0393x over previous
//
#include <hip/hip_runtime.h>

#define BATCH 16
#define PDEG  3          // P == Q == 3
#define MAXSPAN 127      // M == N == 127
#define KLEN  132        // knots per batch: M + P + 2
#define NSAMP 256        // SU == SV
#define NSPANS 126       // KLEN - 2*PDEG
#define GRID_PTS 128     // M+1 == N+1
#define ROWF (GRID_PTS * 3)   // floats per control row = 384

// Scratch in device globals: fully overwritten by basis_kernel before
// eval_kernel reads them (stream-ordered), so harness re-poison of d_ws is
// irrelevant and no ws_size assumption is needed.
//
// NOTE (R3 post-mortem): single-kernel fusion was tried and REGRESSED
// (74.9 -> 77.6 us): it put the knot-scan + redundant per-block v-basis on
// every block's critical path at 1 block/CU. The two-kernel split keeps
// basis at 32 blocks once, eval at 4096 high-residency blocks. Keep it.
__device__ __align__(16) float g_N[2][BATCH][NSAMP][4]; // [axis][b][sample][r]
__device__ int   g_span[2][BATCH][NSAMP];

// grid = (BATCH, 2): blockIdx.y selects axis (0=u, 1=v). 256 threads.
// Knot pipeline in f64: clamp -> double-buffered parallel scan (1 barrier per
// step instead of 2) -> normalize -> span search -> Cox-de Boor degree 3,
// faithful to the reference where() fallbacks.
__global__ void basis_kernel(const float* __restrict__ knot_u,
                             const float* __restrict__ knot_v,
                             const float* __restrict__ u_arr,
                             const float* __restrict__ v_arr)
{
    __shared__ double sA[KLEN];
    __shared__ double sB[KLEN];
    const int b    = blockIdx.x;
    const int axis = blockIdx.y;
    const int tid  = threadIdx.x;

    const float* __restrict__ knots = axis ? knot_v : knot_u;
    const float* __restrict__ t_arr = axis ? v_arr  : u_arr;

    if (tid < KLEN) {
        float w = knots[b * KLEN + tid];
        sA[tid] = (w < 0.0f) ? 1.0e-4 : (double)w;
    }
    __syncthreads();

    // Hillis-Steele inclusive scan, double-buffered: 8 steps, 1 barrier each.
    double* src = sA;
    double* dst = sB;
    for (int off = 1; off < KLEN; off <<= 1) {
        if (tid < KLEN) {
            double v = src[tid];
            if (tid >= off) v += src[tid - off];
            dst[tid] = v;
        }
        __syncthreads();
        double* t_ = src; src = dst; dst = t_;
    }
    // scan result now in src; normalize into dst (distinct buffer -> the
    // reads of src and writes of dst don't alias; one barrier after).
    const double k0  = src[0];
    const double inv = 1.0 / (src[KLEN - 1] - k0);
    if (tid < KLEN) dst[tid] = (src[tid] - k0) * inv;
    __syncthreads();
    const double* __restrict__ kn = dst;

    const double t = (double)t_arr[tid];

    // span: first-argmin over masked = (d > EPS ? d : 1.0), d = t - K[j+deg]
    // linear scan: wave-uniform broadcast loads, independent addresses
    // pipeline well; faithful first-min tie semantics.
    double best = 1.0e300;
    int jmin = 0;
    for (int j = 0; j < NSPANS; ++j) {
        double d = t - kn[j + PDEG];
        double m = (d > 1.0e-8) ? d : 1.0;
        if (m < best) { best = m; jmin = j; }   // strict <: keeps first min
    }
    int span = jmin + PDEG;
    if (span > MAXSPAN) span = MAXSPAN;         // lower clip redundant (>=3)

    // Cox-de Boor, degree 3, exact reference recurrence
    double Ni[PDEG + 1];
    Ni[0] = 1.0;
    for (int k = 1; k <= PDEG; ++k) {
        double saved = 0.0;
        for (int r = 0; r < k; ++r) {
            double K1 = kn[span + r + 1];
            double K2 = kn[span + 1 - k + r];
            double denom = (K1 - t) + (t - K2);
            double temp = (denom == 0.0) ? 1.0e-4 : (Ni[r] / denom);
            Ni[r] = saved + (K1 - t) * temp;
            saved = (t - K2) * temp;
        }
        Ni[k] = saved;
    }

    float4 o4;
    o4.x = (float)Ni[0]; o4.y = (float)Ni[1];
    o4.z = (float)Ni[2]; o4.w = (float)Ni[3];
    *(float4*)&g_N[axis][b][tid][0] = o4;
    g_span[axis][b][tid] = span;
}

// Block = (su, b), thread = sv. Separable contraction.
// ctrl_pts is 3.1 MB total -> fully L2/LLC resident, so phase 1 reads the
// 4 control rows DIRECTLY from global (no LDS staging, no staging barrier).
//   phase 1: tmp[j] = sum_p nu[p] * row_p[j]   (96 threads x float4, global)
//   phase 2: out_d  = sum_q nv[q] * tmp[(vs-3)*3 + 3q + d]
// Single __syncthreads total; LDS = 1.5 KB.
__global__ void __launch_bounds__(256)
eval_kernel(const float* __restrict__ ctrl, float* __restrict__ out)
{
    __shared__ float s_tmp[ROWF];               // 1.5 KB
    const int sv = threadIdx.x;
    const int su = blockIdx.x;
    const int b  = blockIdx.y;

    const int us = g_span[0][b][su];            // uniform across block
    const float4 nu4 = *(const float4*)&g_N[0][b][su][0];   // uniform

    const int vs = g_span[1][b][sv];
    const float4 nv4 = *(const float4*)&g_N[1][b][sv][0];
    const float nv[4] = {nv4.x, nv4.y, nv4.z, nv4.w};

    // phase 1: 384 floats = 96 float4 column-groups; threads 0..95.
    // rows us-3..us are contiguous: row p at float offset p*ROWF = p*96 float4.
    if (sv < ROWF / 4) {
        const float4* __restrict__ r0 = (const float4*)
            (ctrl + ((size_t)b * GRID_PTS + (size_t)(us - PDEG)) * ROWF);
        float4 a0 = r0[0 * 96 + sv];
        float4 a1 = r0[1 * 96 + sv];
        float4 a2 = r0[2 * 96 + sv];
        float4 a3 = r0[3 * 96 + sv];
        float4 t4;
        t4.x = nu4.x * a0.x + nu4.y * a1.x + nu4.z * a2.x + nu4.w * a3.x;
        t4.y = nu4.x * a0.y + nu4.y * a1.y + nu4.z * a2.y + nu4.w * a3.y;
        t4.z = nu4.x * a0.z + nu4.y * a1.z + nu4.z * a2.z + nu4.w * a3.z;
        t4.w = nu4.x * a0.w + nu4.y * a1.w + nu4.z * a2.w + nu4.w * a3.w;
        ((float4*)s_tmp)[sv] = t4;
    }

    __syncthreads();

    // phase 2: contract over q
    const float* tp = s_tmp + (vs - PDEG) * 3;
    float acc0 = 0.f, acc1 = 0.f, acc2 = 0.f;
#pragma unroll
    for (int q = 0; q < 4; ++q) {
        const float w = nv[q];
        acc0 += w * tp[q * 3 + 0];
        acc1 += w * tp[q * 3 + 1];
        acc2 += w * tp[q * 3 + 2];
    }

    const size_t o = (((size_t)b * NSAMP + su) * NSAMP + sv) * 3;
    out[o + 0] = acc0;
    out[o + 1] = acc1;
    out[o + 2] = acc2;
}

extern "C" void kernel_launch(void* const* d_in, const int* in_sizes, int n_in,
                              void* d_out, int out_size, void* d_ws, size_t ws_size,
                              hipStream_t stream) {
    const float* ctrl   = (const float*)d_in[0];  // (16,128,128,3)
    const float* knot_u = (const float*)d_in[1];  // (16,132)
    const float* knot_v = (const float*)d_in[2];  // (16,132)
    const float* u      = (const float*)d_in[3];  // (256,)
    const float* v      = (const float*)d_in[4];  // (256,)
    float* out = (float*)d_out;                   // (16,256,256,3)

    dim3 bgrid(BATCH, 2);
    basis_kernel<<<bgrid, NSAMP, 0, stream>>>(knot_u, knot_v, u, v);

    dim3 egrid(NSAMP, BATCH);
    eval_kernel<<<egrid, NSAMP, 0, stream>>>(ctrl, out);
}